// Round 4
// baseline (2096.558 us; speedup 1.0000x reference)
//
#include <hip/hip_runtime.h>
#include <math.h>

// Problem constants (reference): VOCAB=50257, D=512, B=8, S=2048, E=5
#define NTOK 16384
#define DDIM 512
#define NEXP 5

// ---------------------------------------------------------------------------
// ids dtype insurance: int32 words 1,3,5,7 are high-words (all 0) iff int64
// with values < 2^31; four independent random ids are never all-zero.
// ---------------------------------------------------------------------------
__device__ __forceinline__ int ids_is64(const void* ids) {
    const int* p = (const int*)ids;
    return (p[1] | p[3] | p[5] | p[7]) == 0;
}

// ---------------------------------------------------------------------------
// One block per token. Deliberately scalar / minimal-UB-surface:
//   - no reinterpret_cast vector loads
//   - full 512-element inner loop (no count-based truncation): xm carries the
//     straight-through frac tail exactly like the reference
//   - gate/frac/expert-index math in float64, bit-faithful to a numpy f64
//     re-implementation of the reference (and identical in result to f32)
// ---------------------------------------------------------------------------
__global__ __launch_bounds__(256) void token_moe_simple(
    const void*  __restrict__ idsv,    // (NTOK,) int32 or int64
    const float* __restrict__ emb,     // (VOCAB, 512)
    const float* __restrict__ gate_t,  // (VOCAB, 1)
    const float* __restrict__ W,       // (5, 512, 512)  [e][out][in]
    const float* __restrict__ bias,    // (5, 512)
    float*       __restrict__ out)     // (NTOK, 512)
{
    const int tok = blockIdx.x;
    const int tid = threadIdx.x;

    __shared__ float xm[DDIM];

    const int is64 = ids_is64(idsv);
    const int id = is64 ? (int)((const long long*)idsv)[tok]
                        : ((const int*)idsv)[tok];

    const float gv = gate_t[id];
    const float g  = gv * 512.0f;                 // exact: multiply by 2^9
    // straight-through fractional term, float64 (matches np f64 ref; in f32 it
    // is exactly 0, and folding the f64 value in changes y by ~1e-9 only)
    const double lg  = 1e9 * (double)g;
    const double fr  = (lg - floor(lg)) * 1e-9;
    const float  frf = (float)fr;

    // count = #{ j in [0,512) : (float)j < g }  (g exact in f32 and f64)
    const float fg = floorf(g);
    int count = (int)fg + ((fg < g) ? 1 : 0);
    if (count > DDIM) count = DDIM;
    if (count < 0)    count = 0;

    // expert index: floor(mask.sum() / float(512 // 5)), clamped to [0,4]
    const double msum = (double)count + 512.0 * fr;
    int e = (int)floor(msum / 102.0);
    e = min(max(e, 0), NEXP - 1);

    // stage xm = emb_row * mask into LDS (scalar, coalesced, race-free)
    const float* erow = emb + (size_t)id * DDIM;
    for (int j = tid; j < DDIM; j += 256) {
        const float m = (((float)j < g) ? 1.0f : 0.0f) + frf;
        xm[j] = erow[j] * m;
    }
    __syncthreads();

    // y[o] = sum_d xm[d] * W[e][o][d] + bias[e][o], full 512-term scalar dot
    const float* We = W   + (size_t)e * DDIM * DDIM;
    const float* be = bias + (size_t)e * DDIM;
    for (int half = 0; half < 2; ++half) {
        const int o = tid + half * 256;
        const float* wr = We + (size_t)o * DDIM;
        float acc = 0.0f;
        for (int d = 0; d < DDIM; ++d) {
            acc = fmaf(xm[d], wr[d], acc);
        }
        out[(size_t)tok * DDIM + o] = acc + be[o];
    }
}

// ---------------------------------------------------------------------------
extern "C" void kernel_launch(void* const* d_in, const int* in_sizes, int n_in,
                              void* d_out, int out_size, void* d_ws, size_t ws_size,
                              hipStream_t stream) {
    const void*  ids    = d_in[0];                 // (B,S) token ids
    const float* emb    = (const float*)d_in[1];   // (VOCAB, D)
    const float* gate_t = (const float*)d_in[2];   // (VOCAB, 1)
    const float* W      = (const float*)d_in[3];   // (E, D, D)
    const float* bias   = (const float*)d_in[4];   // (E, D)
    float*       out    = (float*)d_out;           // (B*S, D) fp32

    token_moe_simple<<<NTOK, 256, 0, stream>>>(ids, emb, gate_t, W, bias, out);
}

// Round 5
// 280.898 us; speedup vs baseline: 7.4638x; 7.4638x over previous
//
#include <hip/hip_runtime.h>
#include <math.h>

// Problem constants (reference): VOCAB=50257, D=512, B=8, S=2048, E=5
#define NTOK 16384
#define DDIM 512
#define NEXP 5
#define BT   64          // tokens per GEMM tile

// ---- workspace layout (byte offsets; all 16B-aligned) ----------------------
#define WS_CNT   0           // u32[8]  per-expert counts
#define WS_OFFS  64          // u32[8]  exclusive prefix
#define WS_CUR   128         // u32[8]  scatter cursors
#define WS_EIX   1024        // int[NTOK]
#define WS_ID    (WS_EIX + 4*NTOK)       // int[NTOK]
#define WS_GF    (WS_ID  + 4*NTOK)       // float2[NTOK]
#define WS_REC   (WS_GF  + 8*NTOK)       // int4[NTOK] {tok,id,g,frac} expert-sorted
#define WS_REQ   (WS_REC + 16*NTOK)      // ~787 KB

typedef __attribute__((ext_vector_type(8))) short  bf16x8;
typedef __attribute__((ext_vector_type(4))) float  f32x4;

// ---------------------------------------------------------------------------
// ids dtype insurance (validated in round 4): int32 words 1,3,5,7 are all 0
// iff ids are int64 (<2^31); four random int32 ids are never all zero.
// ---------------------------------------------------------------------------
__device__ __forceinline__ int ids_is64(const void* ids) {
    const int* p = (const int*)ids;
    return (p[1] | p[3] | p[5] | p[7]) == 0;
}

// fp32 -> bf16 bits, round-to-nearest-even (header/codegen-independent)
__device__ __forceinline__ short f2bf(float f) {
    unsigned u = __float_as_uint(f);
    unsigned r = (u + 0x7FFFu + ((u >> 16) & 1u)) >> 16;
    return (short)r;
}

// gate math — bit-faithful to np f64 re-implementation (absmax 0.0 in round 4)
__device__ __forceinline__ void gate_math(float gv, float& g, float& frf,
                                          int& count, int& e) {
    g = gv * 512.0f;
    const double lg = 1e9 * (double)g;
    const double fr = (lg - floor(lg)) * 1e-9;
    frf = (float)fr;
    const float fg = floorf(g);
    count = (int)fg + ((fg < g) ? 1 : 0);
    count = min(max(count, 0), DDIM);
    const double msum = (double)count + 512.0 * fr;
    e = (int)floor(msum / 102.0);          // float(512 // 5) = 102.0
    e = min(max(e, 0), NEXP - 1);
}

// ---------------------------------------------------------------------------
// R0: zero counters/cursors (ws is re-poisoned 0xAA before every launch)
// ---------------------------------------------------------------------------
__global__ void route0(unsigned* __restrict__ ws32) {
    if (threadIdx.x < 48) ws32[threadIdx.x] = 0;   // cnt[8]+offs pad+cur region
}

// ---------------------------------------------------------------------------
// R1: per-token gate math + per-expert counts (wave-aggregated atomics)
// ---------------------------------------------------------------------------
__global__ __launch_bounds__(256) void route1(
    const void* __restrict__ idsv, const float* __restrict__ gate_t,
    int* __restrict__ eix, int* __restrict__ idarr, float2* __restrict__ gf,
    unsigned* __restrict__ cnt)
{
    const int t = blockIdx.x * 256 + threadIdx.x;
    if (t >= NTOK) return;
    const int is64 = ids_is64(idsv);
    const int id = is64 ? (int)((const long long*)idsv)[t]
                        : ((const int*)idsv)[t];
    float g, frf; int count, e;
    gate_math(gate_t[id], g, frf, count, e);
    eix[t] = e; idarr[t] = id; gf[t] = make_float2(g, frf);

    const int lane = threadIdx.x & 63;
    #pragma unroll
    for (int ee = 0; ee < NEXP; ++ee) {
        unsigned long long bm = __ballot(e == ee);
        if (e == ee && lane == (__ffsll((unsigned long long)bm) - 1))
            atomicAdd(&cnt[ee], (unsigned)__popcll(bm));
    }
}

// ---------------------------------------------------------------------------
// R2: 5-element exclusive prefix -> offs; cursors start at offs
// ---------------------------------------------------------------------------
__global__ void route2(const unsigned* __restrict__ cnt,
                       unsigned* __restrict__ offs, unsigned* __restrict__ cur) {
    if (threadIdx.x == 0) {
        unsigned s = 0;
        for (int i = 0; i < NEXP; ++i) { offs[i] = s; cur[i] = s; s += cnt[i]; }
    }
}

// ---------------------------------------------------------------------------
// R3: scatter tokens into expert-sorted record array (wave-aggregated)
// ---------------------------------------------------------------------------
__global__ __launch_bounds__(256) void route3(
    const int* __restrict__ eix, const int* __restrict__ idarr,
    const float2* __restrict__ gf, unsigned* __restrict__ cur,
    int4* __restrict__ rec)
{
    const int t = blockIdx.x * 256 + threadIdx.x;
    if (t >= NTOK) return;
    const int lane = threadIdx.x & 63;
    const int e = eix[t];
    const int id = idarr[t];
    const float2 g2 = gf[t];
    #pragma unroll
    for (int ee = 0; ee < NEXP; ++ee) {
        unsigned long long bm = __ballot(e == ee);
        if (e == ee) {
            const int leader = __ffsll((unsigned long long)bm) - 1;
            int b0 = 0;
            if (lane == leader) b0 = (int)atomicAdd(&cur[ee], (unsigned)__popcll(bm));
            b0 = __shfl(b0, leader, 64);
            const int rank = (int)__popcll(bm & ((1ull << lane) - 1ull));
            rec[b0 + rank] = make_int4(t, id, __float_as_int(g2.x), __float_as_int(g2.y));
        }
    }
}

// ---------------------------------------------------------------------------
// GEMM: per (expert e, 64-token tile). Orientation D[o][t] = W[e]·Xm^T:
//   A = W[e] (o x d, fp32->bf16), B = Xm^T (d x t, gathered+masked+cvt).
// mfma_f32_16x16x32_bf16 layouts (guide §3, m89/m91-verified):
//   A: lane l elem j -> row=l&15 (=o), k=(l>>4)*8+j
//   B: lane l elem j -> col=l&15 (=t), k=(l>>4)*8+j
//   D: lane l reg  r -> col=l&15 (=t), row=(l>>4)*4+r (=o)
// 4 waves split the 512 o-rows (128 each); 8 m-tiles x 4 n-tiles x 16 k-steps.
// No LDS, no barriers; all operand traffic is L2/L3-resident.
// ---------------------------------------------------------------------------
__global__ __launch_bounds__(256, 2) void moe_gemm(
    const float* __restrict__ emb,   // (VOCAB,512)
    const float* __restrict__ W,     // (5,512,512) [e][o][d]
    const float* __restrict__ bias,  // (5,512)
    const int4*  __restrict__ rec,   // expert-sorted {tok,id,g,frac}
    const unsigned* __restrict__ cnt,
    const unsigned* __restrict__ offs,
    float* __restrict__ out)         // (NTOK,512)
{
    const int e  = blockIdx.y;
    const int ce = (int)cnt[e];
    const int tb = blockIdx.x * BT;
    if (tb >= ce) return;
    const int base = (int)offs[e];

    const int lane = threadIdx.x & 63;
    const int w    = threadIdx.x >> 6;   // wave 0..3 -> o-range w*128..+127
    const int c    = lane & 15;
    const int h    = lane >> 4;          // 0..3

    // per-n-tile token info (this lane's column c)
    const float* xrow[4];
    int   tokc[4], valid[4];
    float gc[4], frc[4];
    #pragma unroll
    for (int nt = 0; nt < 4; ++nt) {
        const int pos = tb + nt * 16 + c;
        valid[nt] = (pos < ce);
        const int4 r = rec[base + min(pos, ce - 1)];
        tokc[nt] = r.x;
        xrow[nt] = emb + (size_t)r.y * DDIM;
        gc[nt]   = __int_as_float(r.z);
        frc[nt]  = __int_as_float(r.w);
    }

    const float* We = W + (size_t)e * (DDIM * DDIM);

    f32x4 acc[8][4];
    #pragma unroll
    for (int mt = 0; mt < 8; ++mt)
        #pragma unroll
        for (int nt = 0; nt < 4; ++nt)
            acc[mt][nt] = (f32x4){0.f, 0.f, 0.f, 0.f};

    for (int kk = 0; kk < 16; ++kk) {
        const int k0 = kk * 32 + h * 8;

        bf16x8 a[8];
        #pragma unroll
        for (int mt = 0; mt < 8; ++mt) {
            const float* pa = We + (size_t)(w * 128 + mt * 16 + c) * DDIM + k0;
            const float4 lo = ((const float4*)pa)[0];
            const float4 hi = ((const float4*)pa)[1];
            bf16x8 v;
            v[0]=f2bf(lo.x); v[1]=f2bf(lo.y); v[2]=f2bf(lo.z); v[3]=f2bf(lo.w);
            v[4]=f2bf(hi.x); v[5]=f2bf(hi.y); v[6]=f2bf(hi.z); v[7]=f2bf(hi.w);
            a[mt] = v;
        }

        bf16x8 b[4];
        #pragma unroll
        for (int nt = 0; nt < 4; ++nt) {
            const float* pb = xrow[nt] + k0;
            float4 lo = ((const float4*)pb)[0];
            float4 hi = ((const float4*)pb)[1];
            const float g = gc[nt], fr = frc[nt];
            const float kf = (float)k0;
            lo.x *= ((kf + 0.f < g) ? 1.f : 0.f) + fr;
            lo.y *= ((kf + 1.f < g) ? 1.f : 0.f) + fr;
            lo.z *= ((kf + 2.f < g) ? 1.f : 0.f) + fr;
            lo.w *= ((kf + 3.f < g) ? 1.f : 0.f) + fr;
            hi.x *= ((kf + 4.f < g) ? 1.f : 0.f) + fr;
            hi.y *= ((kf + 5.f < g) ? 1.f : 0.f) + fr;
            hi.z *= ((kf + 6.f < g) ? 1.f : 0.f) + fr;
            hi.w *= ((kf + 7.f < g) ? 1.f : 0.f) + fr;
            bf16x8 v;
            v[0]=f2bf(lo.x); v[1]=f2bf(lo.y); v[2]=f2bf(lo.z); v[3]=f2bf(lo.w);
            v[4]=f2bf(hi.x); v[5]=f2bf(hi.y); v[6]=f2bf(hi.z); v[7]=f2bf(hi.w);
            b[nt] = v;
        }

        #pragma unroll
        for (int mt = 0; mt < 8; ++mt)
            #pragma unroll
            for (int nt = 0; nt < 4; ++nt)
                acc[mt][nt] = __builtin_amdgcn_mfma_f32_16x16x32_bf16(
                    a[mt], b[nt], acc[mt][nt], 0, 0, 0);
    }

    // epilogue: lane writes 4 consecutive o's of one token per (mt,nt)
    #pragma unroll
    for (int mt = 0; mt < 8; ++mt) {
        const int o0 = w * 128 + mt * 16 + h * 4;
        const float4 bv = *(const float4*)(bias + (size_t)e * DDIM + o0);
        #pragma unroll
        for (int nt = 0; nt < 4; ++nt) {
            if (!valid[nt]) continue;
            float4 r;
            r.x = acc[mt][nt][0] + bv.x;
            r.y = acc[mt][nt][1] + bv.y;
            r.z = acc[mt][nt][2] + bv.z;
            r.w = acc[mt][nt][3] + bv.w;
            *(float4*)(out + (size_t)tokc[nt] * DDIM + o0) = r;
        }
    }
}

// ---------------------------------------------------------------------------
// Fallback (proven round-4 kernel) if workspace is too small
// ---------------------------------------------------------------------------
__global__ __launch_bounds__(256) void token_moe_simple(
    const void*  __restrict__ idsv, const float* __restrict__ emb,
    const float* __restrict__ gate_t, const float* __restrict__ W,
    const float* __restrict__ bias, float* __restrict__ out)
{
    const int tok = blockIdx.x;
    const int tid = threadIdx.x;
    __shared__ float xm[DDIM];
    const int is64 = ids_is64(idsv);
    const int id = is64 ? (int)((const long long*)idsv)[tok]
                        : ((const int*)idsv)[tok];
    float g, frf; int count, e;
    gate_math(gate_t[id], g, frf, count, e);
    const float* erow = emb + (size_t)id * DDIM;
    for (int j = tid; j < DDIM; j += 256) {
        const float m = (((float)j < g) ? 1.0f : 0.0f) + frf;
        xm[j] = erow[j] * m;
    }
    __syncthreads();
    const float* We = W + (size_t)e * DDIM * DDIM;
    const float* be = bias + (size_t)e * DDIM;
    for (int half = 0; half < 2; ++half) {
        const int o = tid + half * 256;
        const float* wr = We + (size_t)o * DDIM;
        float acc = 0.0f;
        for (int d = 0; d < DDIM; ++d) acc = fmaf(xm[d], wr[d], acc);
        out[(size_t)tok * DDIM + o] = acc + be[o];
    }
}

// ---------------------------------------------------------------------------
extern "C" void kernel_launch(void* const* d_in, const int* in_sizes, int n_in,
                              void* d_out, int out_size, void* d_ws, size_t ws_size,
                              hipStream_t stream) {
    const void*  ids    = d_in[0];
    const float* emb    = (const float*)d_in[1];
    const float* gate_t = (const float*)d_in[2];
    const float* W      = (const float*)d_in[3];
    const float* bias   = (const float*)d_in[4];
    float*       out    = (float*)d_out;

    if (ws_size < (size_t)WS_REQ) {
        token_moe_simple<<<NTOK, 256, 0, stream>>>(ids, emb, gate_t, W, bias, out);
        return;
    }

    char* ws = (char*)d_ws;
    unsigned* cnt  = (unsigned*)(ws + WS_CNT);
    unsigned* offs = (unsigned*)(ws + WS_OFFS);
    unsigned* cur  = (unsigned*)(ws + WS_CUR);
    int*      eix  = (int*)     (ws + WS_EIX);
    int*      idar = (int*)     (ws + WS_ID);
    float2*   gf   = (float2*)  (ws + WS_GF);
    int4*     rec  = (int4*)    (ws + WS_REC);

    route0<<<1, 64, 0, stream>>>((unsigned*)ws);
    route1<<<NTOK / 256, 256, 0, stream>>>(ids, gate_t, eix, idar, gf, cnt);
    route2<<<1, 64, 0, stream>>>(cnt, offs, cur);
    route3<<<NTOK / 256, 256, 0, stream>>>(eix, idar, gf, cur, rec);
    moe_gemm<<<dim3(NTOK / BT, NEXP), 256, 0, stream>>>(emb, W, bias, rec, cnt, offs, out);
}